// Round 9
// baseline (519.272 us; speedup 1.0000x reference)
//
#include <hip/hip_runtime.h>

// SFT/FiLM layer:
//   gamma = leaky(conv3x3(psi, gamma_w) + gamma_b)
//   beta  = leaky(conv3x3(psi, beta_w)  + beta_b)
//   out[b,h,w,band,c] = gamma[b,h,w,c]*x[b,h,w,band,c] + beta[b,h,w,c]
//
// R6: fused 169us @ Occ 19% (2 blk/CU) -> latency-bound.  R7: LDS 27.7KB,
// 4 blk/CU -> ~131us (inferred; fused dropped below the 164us fill cutoff).
// Model says conv ~10us -> stream phase only ~4.5 TB/s at 16 waves/CU.
// R9: DE-FUSE. conv_gb (1024 blks, barrier-free MFMA, B from L2) writes
// gbuf[pix][128]; film (32768 blks, 512B LDS, 32 waves/CU) streams x->out.
// Fill kernel measured 6.5 TB/s: film should approach it. Plain x loads
// (L3-hot from harness restore), nt stores (don't evict x).

#define LEAKY 0.3f

constexpr int Bc    = 2;
constexpr int Hc    = 128;
constexpr int Wc    = 128;
constexpr int BANDS = 32;
constexpr int C     = 64;
constexpr int CPSI  = 64;
constexpr int COUT2 = 128;           // gamma(64) || beta(64)
constexpr int NPIX  = Bc * Hc * Wc;  // 32768

typedef __attribute__((ext_vector_type(8))) short bf16x8;
typedef __attribute__((ext_vector_type(4))) float f32x4;

// ---- bf16 helpers (RNE) ---------------------------------------------------
__device__ __forceinline__ unsigned short f2bf(float v) {
  unsigned int u = __float_as_uint(v);
  u += 0x7fffu + ((u >> 16) & 1u);
  return (unsigned short)(u >> 16);
}
__device__ __forceinline__ float bf2f(unsigned short h) {
  return __uint_as_float(((unsigned int)h) << 16);
}

// ---------------------------------------------------------------------------
// Preprocess: weights -> w_splitT [9][128 n][128 kp] bf16
// ---------------------------------------------------------------------------
__global__ __launch_bounds__(256) void split_w(
    const float* __restrict__ gw, const float* __restrict__ bw,
    unsigned short* __restrict__ wt)
{
  int o = blockIdx.x * 256 + threadIdx.x;
  int tap = o >> 14;
  int kp  = (o >> 7) & 127;
  int n   = o & 127;
  int cin = kp & 63;
  const float* src = (n < C) ? gw : bw;
  float v = src[((size_t)tap * 64 + cin) * 64 + (n & 63)];
  unsigned short hi = f2bf(v);
  unsigned short r  = (kp < 64) ? hi : f2bf(v - bf2f(hi));
  wt[((size_t)tap << 14) + (size_t)n * 128 + kp] = r;
}

// ---------------------------------------------------------------------------
// conv_gb: 32-pixel strip per block, 4 waves, barrier-free tap loop.
// A (psi hi/lo) from LDS; B direct from L2-resident wt. Writes gbuf (nt).
// ---------------------------------------------------------------------------
constexpr int SMEM_BYTES = 3 * 34 * 136 * 2;        // 27744 B

__global__ __launch_bounds__(256, 4) void conv_gb_mfma(
    const float* __restrict__ psi,
    const unsigned short* __restrict__ wt,
    const float* __restrict__ gbias, const float* __restrict__ bbias,
    float* __restrict__ gbuf)
{
  __shared__ __align__(16) unsigned short As[3][34][136];

  const int tid = threadIdx.x;
  const int blk = blockIdx.x;                   // 1024 blocks
  const int w0  = (blk & 3) * 32;
  const int h   = (blk >> 2) & 127;
  const int b   = blk >> 9;
  const int pix0 = blk * 32;

  for (int c = tid; c < 3 * 34 * 16; c += 256) {
    int ch  = c & 15;
    int col = (c >> 4) % 34;
    int row = (c >> 4) / 34;
    int hh = h + row - 1;
    int ww = w0 + col - 1;
    float4 v = make_float4(0.f, 0.f, 0.f, 0.f);
    if (hh >= 0 && hh < Hc && ww >= 0 && ww < Wc)
      v = *(const float4*)&psi[(((size_t)b * Hc + hh) * Wc + ww) * CPSI + ch * 4];
    ushort4 hi, lo;
    hi.x = f2bf(v.x); lo.x = f2bf(v.x - bf2f(hi.x));
    hi.y = f2bf(v.y); lo.y = f2bf(v.y - bf2f(hi.y));
    hi.z = f2bf(v.z); lo.z = f2bf(v.z - bf2f(hi.z));
    hi.w = f2bf(v.w); lo.w = f2bf(v.w - bf2f(hi.w));
    *(ushort4*)&As[row][col][ch * 4]      = hi;
    *(ushort4*)&As[row][col][64 + ch * 4] = lo;
  }

  const int lane = tid & 63;
  const int wv   = tid >> 6;
  const int nb   = wv * 32;
  const int lrow = lane & 15;
  const int lk8  = (lane >> 4) * 8;

  f32x4 acc[2][2];
#pragma unroll
  for (int i = 0; i < 2; ++i)
#pragma unroll
    for (int j = 0; j < 2; ++j) acc[i][j] = (f32x4){0.f, 0.f, 0.f, 0.f};

  __syncthreads();                    // As ready; no further barriers

  const unsigned short* wl0 = wt + (size_t)(nb + lrow) * 128 + lk8;
  const unsigned short* wl1 = wt + (size_t)(nb + 16 + lrow) * 128 + lk8;

  for (int tap = 0; tap < 9; ++tap) {
    const int r  = tap / 3;
    const int dc = tap % 3;
    const size_t to = (size_t)tap << 14;

#pragma unroll
    for (int kk = 0; kk < 64; kk += 32) {
      bf16x8 ah0 = *(const bf16x8*)&As[r][lrow + dc][kk + lk8];
      bf16x8 ah1 = *(const bf16x8*)&As[r][16 + lrow + dc][kk + lk8];
      bf16x8 al0 = *(const bf16x8*)&As[r][lrow + dc][64 + kk + lk8];
      bf16x8 al1 = *(const bf16x8*)&As[r][16 + lrow + dc][64 + kk + lk8];
      bf16x8 bh0 = *(const bf16x8*)&wl0[to + kk];
      bf16x8 bh1 = *(const bf16x8*)&wl1[to + kk];
      bf16x8 bl0 = *(const bf16x8*)&wl0[to + 64 + kk];
      bf16x8 bl1 = *(const bf16x8*)&wl1[to + 64 + kk];

      acc[0][0] = __builtin_amdgcn_mfma_f32_16x16x32_bf16(ah0, bh0, acc[0][0], 0, 0, 0);
      acc[0][1] = __builtin_amdgcn_mfma_f32_16x16x32_bf16(ah0, bh1, acc[0][1], 0, 0, 0);
      acc[1][0] = __builtin_amdgcn_mfma_f32_16x16x32_bf16(ah1, bh0, acc[1][0], 0, 0, 0);
      acc[1][1] = __builtin_amdgcn_mfma_f32_16x16x32_bf16(ah1, bh1, acc[1][1], 0, 0, 0);
      acc[0][0] = __builtin_amdgcn_mfma_f32_16x16x32_bf16(al0, bh0, acc[0][0], 0, 0, 0);
      acc[0][1] = __builtin_amdgcn_mfma_f32_16x16x32_bf16(al0, bh1, acc[0][1], 0, 0, 0);
      acc[1][0] = __builtin_amdgcn_mfma_f32_16x16x32_bf16(al1, bh0, acc[1][0], 0, 0, 0);
      acc[1][1] = __builtin_amdgcn_mfma_f32_16x16x32_bf16(al1, bh1, acc[1][1], 0, 0, 0);
      acc[0][0] = __builtin_amdgcn_mfma_f32_16x16x32_bf16(ah0, bl0, acc[0][0], 0, 0, 0);
      acc[0][1] = __builtin_amdgcn_mfma_f32_16x16x32_bf16(ah0, bl1, acc[0][1], 0, 0, 0);
      acc[1][0] = __builtin_amdgcn_mfma_f32_16x16x32_bf16(ah1, bl0, acc[1][0], 0, 0, 0);
      acc[1][1] = __builtin_amdgcn_mfma_f32_16x16x32_bf16(ah1, bl1, acc[1][1], 0, 0, 0);
    }
  }

  // epilogue: bias + leaky -> gbuf[pix][128] (nt scalar stores, 64B-coalesced)
#pragma unroll
  for (int nf = 0; nf < 2; ++nf) {
    const int n = nb + nf * 16 + lrow;
    const float bias = (n < C) ? gbias[n] : bbias[n - C];
#pragma unroll
    for (int mf = 0; mf < 2; ++mf) {
#pragma unroll
      for (int rr = 0; rr < 4; ++rr) {
        int m = mf * 16 + (lane >> 4) * 4 + rr;
        float v = acc[mf][nf][rr] + bias;
        __builtin_nontemporal_store(v > 0.f ? v : LEAKY * v,
                                    &gbuf[(size_t)(pix0 + m) * COUT2 + n]);
      }
    }
  }
}

// ---------------------------------------------------------------------------
// film: one pixel per block, 512B LDS, 32 waves/CU. Pure streaming.
// ---------------------------------------------------------------------------
__global__ __launch_bounds__(256) void film(
    const float* __restrict__ x,
    const float* __restrict__ gb,
    float* __restrict__ out)
{
  const int pix = blockIdx.x;
  __shared__ float g[COUT2];
  const int t = threadIdx.x;
  if (t < 32)
    *(float4*)&g[t * 4] = *(const float4*)&gb[(size_t)pix * COUT2 + t * 4];
  __syncthreads();

  const int coff = (t & 7) * 8;
  const size_t base = (size_t)pix * (BANDS * C) + (size_t)t * 8;

  f32x4 x0 = *(const f32x4*)&x[base];        // plain: exploit L3-hot x
  f32x4 x1 = *(const f32x4*)&x[base + 4];
  f32x4 ga0 = *(const f32x4*)&g[coff];
  f32x4 ga1 = *(const f32x4*)&g[coff + 4];
  f32x4 be0 = *(const f32x4*)&g[C + coff];
  f32x4 be1 = *(const f32x4*)&g[C + coff + 4];

  f32x4 o0, o1;
#pragma unroll
  for (int e = 0; e < 4; ++e) {
    o0[e] = fmaf(ga0[e], x0[e], be0[e]);
    o1[e] = fmaf(ga1[e], x1[e], be1[e]);
  }
  __builtin_nontemporal_store(o0, (f32x4*)&out[base]);
  __builtin_nontemporal_store(o1, (f32x4*)&out[base + 4]);
}

// ---------------------------------------------------------------------------
// Fallback 1 (0.29MB <= ws < 17.1MB): R7 fused kernel (measured ~131us).
// ---------------------------------------------------------------------------
__global__ __launch_bounds__(256, 4) void sft_fused(
    const float* __restrict__ psi,
    const unsigned short* __restrict__ wt,
    const float* __restrict__ gbias, const float* __restrict__ bbias,
    const float* __restrict__ x,
    float* __restrict__ out)
{
  __shared__ __align__(16) char smem[SMEM_BYTES];
  auto As = (unsigned short(*)[34][136])smem;
  auto g  = (float(*)[132])smem;

  const int tid = threadIdx.x;
  const int blk = blockIdx.x;
  const int w0  = (blk & 3) * 32;
  const int h   = (blk >> 2) & 127;
  const int b   = blk >> 9;
  const int pix0 = blk * 32;

  for (int c = tid; c < 3 * 34 * 16; c += 256) {
    int ch  = c & 15;
    int col = (c >> 4) % 34;
    int row = (c >> 4) / 34;
    int hh = h + row - 1;
    int ww = w0 + col - 1;
    float4 v = make_float4(0.f, 0.f, 0.f, 0.f);
    if (hh >= 0 && hh < Hc && ww >= 0 && ww < Wc)
      v = *(const float4*)&psi[(((size_t)b * Hc + hh) * Wc + ww) * CPSI + ch * 4];
    ushort4 hi, lo;
    hi.x = f2bf(v.x); lo.x = f2bf(v.x - bf2f(hi.x));
    hi.y = f2bf(v.y); lo.y = f2bf(v.y - bf2f(hi.y));
    hi.z = f2bf(v.z); lo.z = f2bf(v.z - bf2f(hi.z));
    hi.w = f2bf(v.w); lo.w = f2bf(v.w - bf2f(hi.w));
    *(ushort4*)&As[row][col][ch * 4]      = hi;
    *(ushort4*)&As[row][col][64 + ch * 4] = lo;
  }

  const int lane = tid & 63;
  const int wv   = tid >> 6;
  const int nb   = wv * 32;
  const int lrow = lane & 15;
  const int lk8  = (lane >> 4) * 8;

  f32x4 acc[2][2];
#pragma unroll
  for (int i = 0; i < 2; ++i)
#pragma unroll
    for (int j = 0; j < 2; ++j) acc[i][j] = (f32x4){0.f, 0.f, 0.f, 0.f};

  __syncthreads();

  const unsigned short* wl0 = wt + (size_t)(nb + lrow) * 128 + lk8;
  const unsigned short* wl1 = wt + (size_t)(nb + 16 + lrow) * 128 + lk8;

  for (int tap = 0; tap < 9; ++tap) {
    const int r  = tap / 3;
    const int dc = tap % 3;
    const size_t to = (size_t)tap << 14;
#pragma unroll
    for (int kk = 0; kk < 64; kk += 32) {
      bf16x8 ah0 = *(const bf16x8*)&As[r][lrow + dc][kk + lk8];
      bf16x8 ah1 = *(const bf16x8*)&As[r][16 + lrow + dc][kk + lk8];
      bf16x8 al0 = *(const bf16x8*)&As[r][lrow + dc][64 + kk + lk8];
      bf16x8 al1 = *(const bf16x8*)&As[r][16 + lrow + dc][64 + kk + lk8];
      bf16x8 bh0 = *(const bf16x8*)&wl0[to + kk];
      bf16x8 bh1 = *(const bf16x8*)&wl1[to + kk];
      bf16x8 bl0 = *(const bf16x8*)&wl0[to + 64 + kk];
      bf16x8 bl1 = *(const bf16x8*)&wl1[to + 64 + kk];
      acc[0][0] = __builtin_amdgcn_mfma_f32_16x16x32_bf16(ah0, bh0, acc[0][0], 0, 0, 0);
      acc[0][1] = __builtin_amdgcn_mfma_f32_16x16x32_bf16(ah0, bh1, acc[0][1], 0, 0, 0);
      acc[1][0] = __builtin_amdgcn_mfma_f32_16x16x32_bf16(ah1, bh0, acc[1][0], 0, 0, 0);
      acc[1][1] = __builtin_amdgcn_mfma_f32_16x16x32_bf16(ah1, bh1, acc[1][1], 0, 0, 0);
      acc[0][0] = __builtin_amdgcn_mfma_f32_16x16x32_bf16(al0, bh0, acc[0][0], 0, 0, 0);
      acc[0][1] = __builtin_amdgcn_mfma_f32_16x16x32_bf16(al0, bh1, acc[0][1], 0, 0, 0);
      acc[1][0] = __builtin_amdgcn_mfma_f32_16x16x32_bf16(al1, bh0, acc[1][0], 0, 0, 0);
      acc[1][1] = __builtin_amdgcn_mfma_f32_16x16x32_bf16(al1, bh1, acc[1][1], 0, 0, 0);
      acc[0][0] = __builtin_amdgcn_mfma_f32_16x16x32_bf16(ah0, bl0, acc[0][0], 0, 0, 0);
      acc[0][1] = __builtin_amdgcn_mfma_f32_16x16x32_bf16(ah0, bl1, acc[0][1], 0, 0, 0);
      acc[1][0] = __builtin_amdgcn_mfma_f32_16x16x32_bf16(ah1, bl0, acc[1][0], 0, 0, 0);
      acc[1][1] = __builtin_amdgcn_mfma_f32_16x16x32_bf16(ah1, bl1, acc[1][1], 0, 0, 0);
    }
  }

  __syncthreads();
#pragma unroll
  for (int nf = 0; nf < 2; ++nf) {
    const int n = nb + nf * 16 + lrow;
    const float bias = (n < C) ? gbias[n] : bbias[n - C];
#pragma unroll
    for (int mf = 0; mf < 2; ++mf) {
#pragma unroll
      for (int rr = 0; rr < 4; ++rr) {
        int m = mf * 16 + (lane >> 4) * 4 + rr;
        float v = acc[mf][nf][rr] + bias;
        g[m][n] = v > 0.f ? v : LEAKY * v;
      }
    }
  }
  __syncthreads();

  const int c0 = (tid * 4) & 63;
  const size_t pbase = (size_t)pix0 * 2048 + (size_t)tid * 4;
#pragma unroll 4
  for (int p = 0; p < 32; ++p) {
    f32x4 ga = *(const f32x4*)&g[p][c0];
    f32x4 be = *(const f32x4*)&g[p][64 + c0];
    size_t a = pbase + (size_t)p * 2048;
    f32x4 x0 = __builtin_nontemporal_load((const f32x4*)&x[a]);
    f32x4 x1 = __builtin_nontemporal_load((const f32x4*)&x[a + 1024]);
    f32x4 o0, o1;
#pragma unroll
    for (int e = 0; e < 4; ++e) {
      o0[e] = fmaf(ga[e], x0[e], be[e]);
      o1[e] = fmaf(ga[e], x1[e], be[e]);
    }
    __builtin_nontemporal_store(o0, (f32x4*)&out[a]);
    __builtin_nontemporal_store(o1, (f32x4*)&out[a + 1024]);
  }
}

// ---------------------------------------------------------------------------
// Fallback 2 (tiny ws): zero-workspace fused slow path.
// ---------------------------------------------------------------------------
__global__ __launch_bounds__(256) void film_fused_slow(
    const float* __restrict__ psi,
    const float* __restrict__ gw, const float* __restrict__ gbias,
    const float* __restrict__ bw, const float* __restrict__ bbias,
    const float* __restrict__ x,
    float* __restrict__ out)
{
  const int pix = blockIdx.x;
  const int w = pix % Wc;
  const int h = (pix / Wc) % Hc;
  const int b = pix / (Wc * Hc);
  __shared__ float pshal[9 * CPSI];
  __shared__ float g[COUT2];
  const int t = threadIdx.x;

  if (t < 144) {
    int j = t * 4;
    int k = j % CPSI;
    int tap = j / CPSI;
    int r = tap / 3, s = tap % 3;
    int hh = h + r - 1, ww = w + s - 1;
    float4 v = make_float4(0.f, 0.f, 0.f, 0.f);
    if (hh >= 0 && hh < Hc && ww >= 0 && ww < Wc)
      v = *(const float4*)&psi[(((size_t)b * Hc + hh) * Wc + ww) * CPSI + k];
    *(float4*)&pshal[j] = v;
  }
  __syncthreads();

  if (t < COUT2) {
    int c = t & 63;
    const float* W_ = (t < C) ? gw : bw;
    float acc = (t < C) ? gbias[c] : bbias[c];
#pragma unroll 4
    for (int j = 0; j < 576; ++j) acc = fmaf(pshal[j], W_[(size_t)j * 64 + c], acc);
    g[t] = acc > 0.f ? acc : LEAKY * acc;
  }
  __syncthreads();

  const int coff = (t & 7) * 8;
  const size_t base = (size_t)pix * (BANDS * C) + (size_t)t * 8;
  float4 x0 = *(const float4*)&x[base];
  float4 x1 = *(const float4*)&x[base + 4];
  float4 ga0 = *(const float4*)&g[coff];
  float4 ga1 = *(const float4*)&g[coff + 4];
  float4 be0 = *(const float4*)&g[C + coff];
  float4 be1 = *(const float4*)&g[C + coff + 4];
  float4 o0, o1;
  o0.x = fmaf(ga0.x, x0.x, be0.x);
  o0.y = fmaf(ga0.y, x0.y, be0.y);
  o0.z = fmaf(ga0.z, x0.z, be0.z);
  o0.w = fmaf(ga0.w, x0.w, be0.w);
  o1.x = fmaf(ga1.x, x1.x, be1.x);
  o1.y = fmaf(ga1.y, x1.y, be1.y);
  o1.z = fmaf(ga1.z, x1.z, be1.z);
  o1.w = fmaf(ga1.w, x1.w, be1.w);
  *(float4*)&out[base] = o0;
  *(float4*)&out[base + 4] = o1;
}

extern "C" void kernel_launch(void* const* d_in, const int* in_sizes, int n_in,
                              void* d_out, int out_size, void* d_ws, size_t ws_size,
                              hipStream_t stream) {
  const float* x     = (const float*)d_in[0];
  const float* psi   = (const float*)d_in[1];
  const float* gw    = (const float*)d_in[2];
  const float* gbias = (const float*)d_in[3];
  const float* bw    = (const float*)d_in[4];
  const float* bbias = (const float*)d_in[5];
  float* out = (float*)d_out;

  const size_t wsplit_bytes = (size_t)9 * 128 * 128 * 2;   //  0.29 MB
  const size_t gbuf_bytes   = (size_t)NPIX * COUT2 * 4;    // 16.78 MB

  if (ws_size >= wsplit_bytes + gbuf_bytes) {
    unsigned short* wtp = (unsigned short*)d_ws;
    float* gbuf = (float*)((char*)d_ws + wsplit_bytes);
    split_w<<<9 * 128 * 128 / 256, 256, 0, stream>>>(gw, bw, wtp);
    conv_gb_mfma<<<NPIX / 32, 256, 0, stream>>>(psi, wtp, gbias, bbias, gbuf);
    film<<<NPIX, 256, 0, stream>>>(x, gbuf, out);
  } else if (ws_size >= wsplit_bytes) {
    unsigned short* wtp = (unsigned short*)d_ws;
    split_w<<<9 * 128 * 128 / 256, 256, 0, stream>>>(gw, bw, wtp);
    sft_fused<<<NPIX / 32, 256, 0, stream>>>(psi, wtp, gbias, bbias, x, out);
  } else {
    film_fused_slow<<<NPIX, 256, 0, stream>>>(psi, gw, gbias, bw, bbias, x, out);
  }
}